// Round 7
// baseline (783.577 us; speedup 1.0000x reference)
//
#include <hip/hip_runtime.h>

// AutoregressiveForecaster R7: R6 structure + corrected launch_bounds.
// 2-layer LSTM(H=64) + MLP head, 20 autoregressive steps, 24-window, B=8192.
//
//  - 512 blocks x 512 threads (8 waves). Block owns ONE 16-batch M-tile.
//  - Waves 0-3 (G0): layer-0 worker for unit-quarter k=wave. Waves 4-7 (G1):
//    layer-1 worker for quarter k=wave-4. Iteration i: G0 does L0(t=i),
//    G1 does L1(t=i-1). 25 iters/step, ping-pong h buffers, 1 barrier/iter.
//  - UNIFORM code across waves (no divergent register pressure).
//  - launch_bounds(512, 2): empirically hipcc treats arg2 as min BLOCKS/CU
//    (R5/R6 with (512,4) gave VGPR cap 64 = 32 waves/CU and massive scratch
//    spills, 40MB WRITE_SIZE). 2 blocks/CU -> 16 waves/CU, 128-VGPR cap,
//    demand ~120 fits with zero spill.
//  - Fused gates: 8 trans/unit-step. Weights pre-scaled by log2e (2x g-gate).
//  - MLP weights in LDS (cold path).

typedef _Float16 f16x8 __attribute__((ext_vector_type(8)));
typedef float f32x4 __attribute__((ext_vector_type(4)));

#define NBLK 512
#define NTHR 512
#define SRB  160   // h row stride bytes (80 f16)

__device__ __forceinline__ float rcp_(float x) { return __builtin_amdgcn_rcpf(x); }
__device__ __forceinline__ float exp2_(float x) { return __builtin_amdgcn_exp2f(x); }
__device__ __forceinline__ f32x4 mfma16(uint4 a, uint4 b, f32x4 c) {
  return __builtin_amdgcn_mfma_f32_16x16x32_f16(
      __builtin_bit_cast(f16x8, a), __builtin_bit_cast(f16x8, b), c, 0, 0, 0);
}
__device__ __forceinline__ uint4 pack8s(const float* p, float s) {
  union { uint4 u; _Float16 h[8]; } r;
  #pragma unroll
  for (int i = 0; i < 8; ++i) r.h[i] = (_Float16)(p[i] * s);
  return r.u;
}

__global__ __launch_bounds__(NTHR, 2) void lstm_forecast(
    const float* __restrict__ x,
    const float* __restrict__ Wih0, const float* __restrict__ Whh0,
    const float* __restrict__ bih0, const float* __restrict__ bhh0,
    const float* __restrict__ Wih1, const float* __restrict__ Whh1,
    const float* __restrict__ bih1, const float* __restrict__ bhh1,
    const float* __restrict__ W1,   const float* __restrict__ b1,
    const float* __restrict__ W2,   const float* __restrict__ b2,
    const float* __restrict__ damping, const int* __restrict__ stepsPtr,
    float* __restrict__ out)
{
  __shared__ __align__(16) _Float16 h1s[2][1280];   // [parity][16 x 80]
  __shared__ __align__(16) _Float16 h2s[2][1280];
  __shared__ __align__(16) float    win[24 * 16];
  __shared__ __align__(16) uint4    wfm[4][64];     // MLP W1 frags
  __shared__ float w2s[32], b1s[32];
  __shared__ float pm[2][16];

  const int tid   = threadIdx.x;
  const int wave  = tid >> 6;
  const int lane  = tid & 63;
  const int cc    = lane & 15;
  const int hi    = lane >> 4;
  const int group = wave >> 2;       // 0: layer-0 worker, 1: layer-1 worker
  const int k     = wave & 3;        // unit quarter
  const int b0g   = blockIdx.x * 16;
  const float L2E = 1.44269504089f;

  // ---- weight B-fragments into VGPRs (uniform shape, group-dependent data) --
  const float* srcA = group ? Wih1 : Whh0;
  const float* srcB = group ? Whh1 : Whh0;     // G0: dummy, scaled by 0
  const float  sB   = group ? 1.0f : 0.0f;
  uint4 wF[4][4];
  float wxv[4], bxv[4];
  #pragma unroll
  for (int gt = 0; gt < 4; ++gt) {
    float sc = (gt == 2) ? 2.0f * L2E : L2E;
    int row = gt * 64 + k * 16 + cc;
    #pragma unroll
    for (int f = 0; f < 2; ++f) {
      int col = f * 32 + hi * 8;
      wF[gt][f]     = pack8s(srcA + row * 64 + col, sc);
      wF[gt][2 + f] = pack8s(srcB + row * 64 + col, sc * sB);
    }
    bxv[gt] = (group ? (bih1[row] + bhh1[row]) : (bih0[row] + bhh0[row])) * sc;
    wxv[gt] = group ? 0.0f : Wih0[row] * sc;
  }
  // MLP weights -> LDS (cold path; keeps hot-loop VGPR low)
  for (int e = tid; e < 256; e += NTHR) {
    int l = e & 63, f = (e >> 6) & 1, n = e >> 7;
    wfm[n * 2 + f][l] =
        pack8s(W1 + (n * 16 + (l & 15)) * 64 + f * 32 + (l >> 4) * 8, 1.0f);
  }
  if (tid < 32) { w2s[tid] = W2[tid]; b1s[tid] = b1[tid]; }
  // window init: win[t*16+b] = x[(b0g+b)*24 + t]
  for (int e = tid; e < 384; e += NTHR) {
    int b = e & 15, t = e >> 4;
    win[t * 16 + b] = x[(b0g + b) * 24 + t];
  }
  const float alpha  = rcp_(1.0f + exp2_(-L2E * damping[0]));
  const int   nsteps = stepsPtr[0];
  const float b2v    = b2[0];
  __syncthreads();

  const int offA = cc * SRB + hi * 16;      // A-frag byte offset
  float prevp = 0.0f;

#define ITER(P, WM)                                                            \
  do {                                                                         \
    const char* rb1 = (const char*)h1s[P];                                     \
    const char* rb2 = (const char*)h2s[P];                                     \
    uint4 a1lo = *(const uint4*)(rb1 + offA);                                  \
    uint4 a1hi = *(const uint4*)(rb1 + offA + 64);                             \
    uint4 a2lo = *(const uint4*)(rb2 + offA);                                  \
    uint4 a2hi = *(const uint4*)(rb2 + offA + 64);                             \
    float4 xw = *(const float4*)&win[ph * 16 + hi * 4];                        \
    f32x4 acc[4];                                                              \
    _Pragma("unroll")                                                          \
    for (int gt = 0; gt < 4; ++gt) {                                           \
      f32x4 ai;                                                                \
      ai[0] = fmaf(xw.x, wxv[gt], bxv[gt]);                                    \
      ai[1] = fmaf(xw.y, wxv[gt], bxv[gt]);                                    \
      ai[2] = fmaf(xw.z, wxv[gt], bxv[gt]);                                    \
      ai[3] = fmaf(xw.w, wxv[gt], bxv[gt]);                                    \
      f32x4 tv = mfma16(a1lo, wF[gt][0], ai);                                  \
      tv = mfma16(a1hi, wF[gt][1], tv);                                        \
      tv = mfma16(a2lo, wF[gt][2], tv);                                        \
      acc[gt] = mfma16(a2hi, wF[gt][3], tv);                                   \
    }                                                                          \
    char* dst = group ? (char*)h2s[P ^ 1] : (char*)h1s[P ^ 1];                 \
    _Pragma("unroll")                                                          \
    for (int r = 0; r < 4; ++r) {                                              \
      float xx = exp2_(-acc[0][r]);                                            \
      float xf = exp2_(-acc[1][r]);                                            \
      float yy = exp2_(-acc[2][r]);                                            \
      float xo = exp2_(-acc[3][r]);                                            \
      float ig = (1.0f - yy) * rcp_((1.0f + xx) * (1.0f + yy));                \
      float fh = rcp_(1.0f + xf);                                              \
      float cv = (WM) * fmaf(fh, cst[r], ig);                                  \
      cst[r] = cv;                                                             \
      float z  = exp2_(-2.88539008178f * cv);                                  \
      float hv = (1.0f - z) * rcp_((1.0f + xo) * (1.0f + z));                  \
      *(_Float16*)(dst + (hi * 4 + r) * SRB + (k * 16 + cc) * 2) =             \
          (_Float16)hv;                                                        \
    }                                                                          \
    __syncthreads();                                                           \
    ph = (ph >= 23) ? 0 : ph + 1;                                              \
  } while (0)

  #pragma unroll 1
  for (int s = 0; s < nsteps; ++s) {
    // zero parity-0 buffers (read at iter 0)
    {
      unsigned* z1 = (unsigned*)h1s[0];
      unsigned* z2 = (unsigned*)h2s[0];
      for (int e = tid; e < 640; e += NTHR) { z1[e] = 0; z2[e] = 0; }
    }
    __syncthreads();

    float cst[4] = {0, 0, 0, 0};
    int ph = s; while (ph >= 24) ph -= 24;

    const float wm0 = group ? 0.0f : 1.0f;   // suppress G1's t=-1 garbage
    ITER(0, wm0);
    #pragma unroll 1
    for (int ii = 0; ii < 12; ++ii) {
      ITER(1, 1.0f);
      ITER(0, 1.0f);
    }
    // after 25 iters: h2(23) sits in h2s[1]

    // ---- MLP head (waves 0,1) ----
    if (wave < 2) {
      uint4 hflo = *(const uint4*)((const char*)h2s[1] + offA);
      uint4 hfhi = *(const uint4*)((const char*)h2s[1] + offA + 64);
      uint4 m0 = wfm[wave * 2 + 0][lane];
      uint4 m1 = wfm[wave * 2 + 1][lane];
      float b1vv = b1s[wave * 16 + cc];
      float w2v  = w2s[wave * 16 + cc];
      f32x4 am;
      #pragma unroll
      for (int r = 0; r < 4; ++r) am[r] = b1vv;
      am = mfma16(hflo, m0, am);
      am = mfma16(hfhi, m1, am);
      float yp[4];
      #pragma unroll
      for (int r = 0; r < 4; ++r) yp[r] = fmaxf(am[r], 0.0f) * w2v;
      #pragma unroll
      for (int mask = 1; mask <= 8; mask <<= 1) {
        #pragma unroll
        for (int r = 0; r < 4; ++r) yp[r] += __shfl_xor(yp[r], mask);
      }
      if (cc == 0) {
        #pragma unroll
        for (int r = 0; r < 4; ++r) pm[wave][hi * 4 + r] = yp[r];
      }
    }
    __syncthreads();

    if (wave == 0 && lane < 16) {
      float y = pm[0][lane] + pm[1][lane] + b2v;
      float pd = (s == 0) ? y : fmaf(y, 1.0f - alpha, prevp * (alpha * 0.5f));
      prevp = pd;
      int slot = s; while (slot >= 24) slot -= 24;
      win[slot * 16 + lane] = pd;
      out[(long)(b0g + lane) * nsteps + s] = pd;
    }
    __syncthreads();
  } // s
#undef ITER
}

extern "C" void kernel_launch(void* const* d_in, const int* in_sizes, int n_in,
                              void* d_out, int out_size, void* d_ws, size_t ws_size,
                              hipStream_t stream) {
  (void)in_sizes; (void)n_in; (void)out_size; (void)d_ws; (void)ws_size;
  lstm_forecast<<<NBLK, NTHR, 0, stream>>>(
      (const float*)d_in[0],
      (const float*)d_in[1],  (const float*)d_in[2],
      (const float*)d_in[3],  (const float*)d_in[4],
      (const float*)d_in[5],  (const float*)d_in[6],
      (const float*)d_in[7],  (const float*)d_in[8],
      (const float*)d_in[9],  (const float*)d_in[10],
      (const float*)d_in[11], (const float*)d_in[12],
      (const float*)d_in[13], (const int*)d_in[14],
      (float*)d_out);
}

// Round 8
// 661.574 us; speedup vs baseline: 1.1844x; 1.1844x over previous
//
#include <hip/hip_runtime.h>

// AutoregressiveForecaster R8: R4 structure + 2 independent flag-synced groups
// per block + fused-7-trans gates.
// 2-layer LSTM(H=64) + MLP head, 20 autoregressive steps, 24-window, B=8192.
//
//  - 256 blocks x 512 threads = 2 groups of 4 waves. Each group owns an
//    independent 16-batch M-tile; groups never sync with each other ->
//    2 blocks/CU x 2 groups = 4 independent dependency chains per CU.
//  - Group sync via per-group LDS counter (lane0 release-add, all-lane
//    acquire spin). No __syncthreads after setup.
//  - Wave wg of group owns gate-tiles {wg,wg+4,wg+8,wg+12} = gates i,f,g,o of
//    units [16wg,16wg+16): elementwise lane-local, c in registers.
//  - Pipelined: iter t computes L1(t) [K=128: h1(t)|h2(t-1)] + L0(t+1) [K=64],
//    ping-pong h buffers, 1 sync/iter.
//  - Fused-7 gates: c = [c*P + (1-yy)Q]*rcp(P*Q), P=(1+xx)(1+yy), Q=1+xf;
//    h = (1-z)*rcp((1+xo)(1+z)) -> 5 exp2 + 2 rcp per unit-step (R4: 5+5).
//  - Weights pre-scaled by log2e (2x g-gate), B-frags in VGPRs (24 uint4).

typedef _Float16 f16x8 __attribute__((ext_vector_type(8)));
typedef float f32x4 __attribute__((ext_vector_type(4)));

#define NBLK 256
#define NTHR 512
#define SRB  160   // h row stride bytes (80 f16)

__device__ __forceinline__ float rcp_(float x) { return __builtin_amdgcn_rcpf(x); }
__device__ __forceinline__ float exp2_(float x) { return __builtin_amdgcn_exp2f(x); }
__device__ __forceinline__ f32x4 mfma16(uint4 a, uint4 b, f32x4 c) {
  return __builtin_amdgcn_mfma_f32_16x16x32_f16(
      __builtin_bit_cast(f16x8, a), __builtin_bit_cast(f16x8, b), c, 0, 0, 0);
}
__device__ __forceinline__ uint4 pack8s(const float* p, float s) {
  union { uint4 u; _Float16 h[8]; } r;
  #pragma unroll
  for (int i = 0; i < 8; ++i) r.h[i] = (_Float16)(p[i] * s);
  return r.u;
}
// fused LSTM gate update; pre-activations pre-scaled by log2e (2x for g-gate).
// returns h, updates c in place. Valid for c==0 (prologue).
__device__ __forceinline__ float gatestep(float aI, float aF, float aG, float aO,
                                          float& cst) {
  float xx = exp2_(-aI), xf = exp2_(-aF), yy = exp2_(-aG), xo = exp2_(-aO);
  float P = (1.0f + xx) * (1.0f + yy);
  float Q = 1.0f + xf;
  float N = fmaf(cst, P * Q - P * xf, (1.0f - yy) * Q); // cst*P + (1-yy)*Q
  float cv = N * rcp_(P * Q);
  cst = cv;
  float z = exp2_(-2.88539008178f * cv);
  return (1.0f - z) * rcp_((1.0f + xo) * (1.0f + z));
}

__global__ __launch_bounds__(NTHR, 2) void lstm_forecast(
    const float* __restrict__ x,
    const float* __restrict__ Wih0, const float* __restrict__ Whh0,
    const float* __restrict__ bih0, const float* __restrict__ bhh0,
    const float* __restrict__ Wih1, const float* __restrict__ Whh1,
    const float* __restrict__ bih1, const float* __restrict__ bhh1,
    const float* __restrict__ W1,   const float* __restrict__ b1,
    const float* __restrict__ W2,   const float* __restrict__ b2,
    const float* __restrict__ damping, const int* __restrict__ stepsPtr,
    float* __restrict__ out)
{
  __shared__ __align__(16) _Float16 h1s[2][2][1280];  // [group][parity][16x80]
  __shared__ __align__(16) _Float16 h2s[2][2][1280];
  __shared__ __align__(16) float    win[2][24 * 16];
  __shared__ float pm[2][2][16];
  __shared__ int   cnt[2];

  const int tid  = threadIdx.x;
  const int wave = tid >> 6;
  const int lane = tid & 63;
  const int cc   = lane & 15;
  const int hi   = lane >> 4;
  const int g    = wave >> 2;
  const int wg   = wave & 3;
  const int b0g  = blockIdx.x * 32 + g * 16;
  const float L2E = 1.44269504089f;

  uint4 wB0[4][2], wB1[4][2], wB2[4][2];
  float bias0v[4], wih0v[4];
  f32x4 bi1[4];
  #pragma unroll
  for (int gt = 0; gt < 4; ++gt) {
    float sc = (gt == 2) ? 2.0f * L2E : L2E;
    int row = (wg + 4 * gt) * 16 + cc;
    #pragma unroll
    for (int f = 0; f < 2; ++f) {
      int col = f * 32 + hi * 8;
      wB0[gt][f] = pack8s(Whh0 + row * 64 + col, sc);
      wB1[gt][f] = pack8s(Wih1 + row * 64 + col, sc);
      wB2[gt][f] = pack8s(Whh1 + row * 64 + col, sc);
    }
    bias0v[gt] = (bih0[row] + bhh0[row]) * sc;
    wih0v[gt]  = Wih0[row] * sc;
    float b1c  = (bih1[row] + bhh1[row]) * sc;
    #pragma unroll
    for (int r = 0; r < 4; ++r) bi1[gt][r] = b1c;
  }
  uint4 wM[2];
  {
    int row = (wg & 1) * 16 + cc;
    wM[0] = pack8s(W1 + row * 64 + hi * 8, 1.0f);
    wM[1] = pack8s(W1 + row * 64 + 32 + hi * 8, 1.0f);
  }
  const float w2v  = W2[(wg & 1) * 16 + cc];
  const float b1vv = b1[(wg & 1) * 16 + cc];
  const float alpha  = rcp_(1.0f + exp2_(-L2E * damping[0]));
  const int   nsteps = stepsPtr[0];
  const float b2v    = b2[0];

  for (int e = (tid & 255); e < 384; e += 256) {
    int b = e & 15, t = e >> 4;
    win[g][t * 16 + b] = x[(b0g + b) * 24 + t];
  }
  if (tid < 2) cnt[tid] = 0;
  __syncthreads();

  int syncTgt = 0;
  auto gsync = [&]() {
    syncTgt += 4;
    if (lane == 0)
      __hip_atomic_fetch_add(&cnt[g], 1, __ATOMIC_RELEASE,
                             __HIP_MEMORY_SCOPE_WORKGROUP);
    while (__hip_atomic_load(&cnt[g], __ATOMIC_ACQUIRE,
                             __HIP_MEMORY_SCOPE_WORKGROUP) < syncTgt) { }
  };

  char* h1b[2] = { (char*)h1s[g][0], (char*)h1s[g][1] };
  char* h2b[2] = { (char*)h2s[g][0], (char*)h2s[g][1] };
  float* winw = win[g];
  const int offA = cc * SRB + hi * 16;
  const int offS = (wg * 16 + cc) * 2;
  float prevp = 0.0f;

  for (int s = 0; s < nsteps; ++s) {
    float c1[4] = {0, 0, 0, 0}, c2s[4] = {0, 0, 0, 0};

    {
      float4 xw = *(const float4*)&winw[(s % 24) * 16 + hi * 4];
      float xa[4] = {xw.x, xw.y, xw.z, xw.w};
      #pragma unroll
      for (int r = 0; r < 4; ++r) {
        float hv = gatestep(fmaf(xa[r], wih0v[0], bias0v[0]),
                            fmaf(xa[r], wih0v[1], bias0v[1]),
                            fmaf(xa[r], wih0v[2], bias0v[2]),
                            fmaf(xa[r], wih0v[3], bias0v[3]), c1[r]);
        *(_Float16*)(h1b[0] + (hi * 4 + r) * SRB + offS) = (_Float16)hv;
      }
    }
    gsync();
    uint4 a1lo = *(const uint4*)(h1b[0] + offA);
    uint4 a1hi = *(const uint4*)(h1b[0] + offA + 64);
    uint4 a2lo = make_uint4(0, 0, 0, 0), a2hi = make_uint4(0, 0, 0, 0);

    for (int t = 0; t < 23; ++t) {
      int pb = (t + 1) & 1;
      int ph = s + t + 1; if (ph >= 24) ph -= 24;
      float4 xw = *(const float4*)&winw[ph * 16 + hi * 4];
      float xa[4] = {xw.x, xw.y, xw.z, xw.w};

      f32x4 acc1[4], acc0[4];
      #pragma unroll
      for (int gt = 0; gt < 4; ++gt) {
        f32x4 tv = mfma16(a1lo, wB1[gt][0], bi1[gt]);
        tv = mfma16(a1hi, wB1[gt][1], tv);
        tv = mfma16(a2lo, wB2[gt][0], tv);
        acc1[gt] = mfma16(a2hi, wB2[gt][1], tv);
      }
      #pragma unroll
      for (int gt = 0; gt < 4; ++gt) {
        f32x4 ai;
        #pragma unroll
        for (int r = 0; r < 4; ++r) ai[r] = fmaf(xa[r], wih0v[gt], bias0v[gt]);
        f32x4 tv = mfma16(a1lo, wB0[gt][0], ai);
        acc0[gt] = mfma16(a1hi, wB0[gt][1], tv);
      }

      char* h2d = h2b[pb];
      char* h1d = h1b[pb];
      #pragma unroll
      for (int r = 0; r < 4; ++r) {
        float hv = gatestep(acc1[0][r], acc1[1][r], acc1[2][r], acc1[3][r], c2s[r]);
        *(_Float16*)(h2d + (hi * 4 + r) * SRB + offS) = (_Float16)hv;
      }
      #pragma unroll
      for (int r = 0; r < 4; ++r) {
        float hv = gatestep(acc0[0][r], acc0[1][r], acc0[2][r], acc0[3][r], c1[r]);
        *(_Float16*)(h1d + (hi * 4 + r) * SRB + offS) = (_Float16)hv;
      }
      gsync();
      a1lo = *(const uint4*)(h1b[pb] + offA);
      a1hi = *(const uint4*)(h1b[pb] + offA + 64);
      a2lo = *(const uint4*)(h2b[pb] + offA);
      a2hi = *(const uint4*)(h2b[pb] + offA + 64);
    } // t

    {
      f32x4 acc1[4];
      #pragma unroll
      for (int gt = 0; gt < 4; ++gt) {
        f32x4 tv = mfma16(a1lo, wB1[gt][0], bi1[gt]);
        tv = mfma16(a1hi, wB1[gt][1], tv);
        tv = mfma16(a2lo, wB2[gt][0], tv);
        acc1[gt] = mfma16(a2hi, wB2[gt][1], tv);
      }
      #pragma unroll
      for (int r = 0; r < 4; ++r) {
        float cv = c2s[r];
        float hv = gatestep(acc1[0][r], acc1[1][r], acc1[2][r], acc1[3][r], cv);
        *(_Float16*)(h2b[0] + (hi * 4 + r) * SRB + offS) = (_Float16)hv;
      }
    }
    gsync();

    if (wg < 2) {
      uint4 hflo = *(const uint4*)(h2b[0] + offA);
      uint4 hfhi = *(const uint4*)(h2b[0] + offA + 64);
      f32x4 am;
      #pragma unroll
      for (int r = 0; r < 4; ++r) am[r] = b1vv;
      am = mfma16(hflo, wM[0], am);
      am = mfma16(hfhi, wM[1], am);
      float yp[4];
      #pragma unroll
      for (int r = 0; r < 4; ++r) yp[r] = fmaxf(am[r], 0.0f) * w2v;
      #pragma unroll
      for (int mask = 1; mask <= 8; mask <<= 1) {
        #pragma unroll
        for (int r = 0; r < 4; ++r) yp[r] += __shfl_xor(yp[r], mask);
      }
      if (cc == 0) {
        #pragma unroll
        for (int r = 0; r < 4; ++r) pm[g][wg][hi * 4 + r] = yp[r];
      }
    }
    gsync();

    if (wg == 0 && lane < 16) {
      float y = pm[g][0][lane] + pm[g][1][lane] + b2v;
      float pd = (s == 0) ? y : fmaf(y, 1.0f - alpha, prevp * (alpha * 0.5f));
      prevp = pd;
      winw[(s % 24) * 16 + lane] = pd;
      out[(long)(b0g + lane) * nsteps + s] = pd;
    }
    gsync();
  } // s
}

extern "C" void kernel_launch(void* const* d_in, const int* in_sizes, int n_in,
                              void* d_out, int out_size, void* d_ws, size_t ws_size,
                              hipStream_t stream) {
  (void)in_sizes; (void)n_in; (void)out_size; (void)d_ws; (void)ws_size;
  lstm_forecast<<<NBLK, NTHR, 0, stream>>>(
      (const float*)d_in[0],
      (const float*)d_in[1],  (const float*)d_in[2],
      (const float*)d_in[3],  (const float*)d_in[4],
      (const float*)d_in[5],  (const float*)d_in[6],
      (const float*)d_in[7],  (const float*)d_in[8],
      (const float*)d_in[9],  (const float*)d_in[10],
      (const float*)d_in[11], (const float*)d_in[12],
      (const float*)d_in[13], (const int*)d_in[14],
      (float*)d_out);
}

// Round 9
// 596.958 us; speedup vs baseline: 1.3126x; 1.1082x over previous
//
#include <hip/hip_runtime.h>

// AutoregressiveForecaster R9: R4 base (best: 640us) + fused-7 gates (R8-verified)
// + SRB 144 (bank-conflict fix). 2-layer LSTM(H=64) + MLP head, 20 steps, B=8192.
//
//  - 512 blocks x 256 threads (4 waves), block owns one 16-batch MFMA M-tile.
//    2 blocks/CU -> 2 independent barrier domains per CU (structural max:
//    batch/16 = 512 tiles).
//  - Wave w owns gate-tiles {w,w+4,w+8,w+12} = gates i,f,g,o of units
//    [16w,16w+16): elementwise lane-local, c-state in registers.
//  - Pipelined: iter t computes L1(t) [K=128: h1(t)|h2(t-1)] and L0(t+1)
//    [K=64: h1(t)], ping-pong h staging, 1 __syncthreads/iter.
//  - Fused-7 gates (R8-verified numerics): P=(1+xx)(1+yy), Q=1+xf,
//    c' = (c*P + (1-yy)Q)*rcp(PQ), h = (1-z)*rcp((1+xo)(1+z)) ->
//    5 exp2 + 2 rcp per unit-step (R4 had 5+5).
//  - SRB=144: A-frag ds_read_b128 stride 36 words -> 2-way bank alias (free)
//    vs 160's 4-way (1.58x). Still 16B-aligned.
//  - Weights pre-scaled by log2e (2x g-gate), B-frags in VGPRs (24 uint4).

typedef _Float16 f16x8 __attribute__((ext_vector_type(8)));
typedef float f32x4 __attribute__((ext_vector_type(4)));

#define NBLK 512
#define NTHR 256
#define SRB  144   // h row stride bytes (72 f16; 64 used + 8 pad)

__device__ __forceinline__ float rcp_(float x) { return __builtin_amdgcn_rcpf(x); }
__device__ __forceinline__ float exp2_(float x) { return __builtin_amdgcn_exp2f(x); }
__device__ __forceinline__ f32x4 mfma16(uint4 a, uint4 b, f32x4 c) {
  return __builtin_amdgcn_mfma_f32_16x16x32_f16(
      __builtin_bit_cast(f16x8, a), __builtin_bit_cast(f16x8, b), c, 0, 0, 0);
}
__device__ __forceinline__ uint4 pack8s(const float* p, float s) {
  union { uint4 u; _Float16 h[8]; } r;
  #pragma unroll
  for (int i = 0; i < 8; ++i) r.h[i] = (_Float16)(p[i] * s);
  return r.u;
}
// fused LSTM gate update; pre-activations pre-scaled by log2e (2x for g-gate).
// returns h, updates c in place. Valid for c==0 (prologue).
__device__ __forceinline__ float gatestep(float aI, float aF, float aG, float aO,
                                          float& cst) {
  float xx = exp2_(-aI), xf = exp2_(-aF), yy = exp2_(-aG), xo = exp2_(-aO);
  float P = (1.0f + xx) * (1.0f + yy);
  float Q = 1.0f + xf;
  float N = fmaf(cst, P, (1.0f - yy) * Q);   // c*P + (1-yy)*Q
  float cv = N * rcp_(P * Q);
  cst = cv;
  float z = exp2_(-2.88539008178f * cv);
  return (1.0f - z) * rcp_((1.0f + xo) * (1.0f + z));
}

__global__ __launch_bounds__(NTHR, 2) void lstm_forecast(
    const float* __restrict__ x,
    const float* __restrict__ Wih0, const float* __restrict__ Whh0,
    const float* __restrict__ bih0, const float* __restrict__ bhh0,
    const float* __restrict__ Wih1, const float* __restrict__ Whh1,
    const float* __restrict__ bih1, const float* __restrict__ bhh1,
    const float* __restrict__ W1,   const float* __restrict__ b1,
    const float* __restrict__ W2,   const float* __restrict__ b2,
    const float* __restrict__ damping, const int* __restrict__ stepsPtr,
    float* __restrict__ out)
{
  __shared__ __align__(16) char h1s[2][16 * SRB];
  __shared__ __align__(16) char h2s[2][16 * SRB];
  __shared__ __align__(16) float win[24 * 16];
  __shared__ __align__(16) float pm[2][16];

  const int tid  = threadIdx.x;
  const int wave = tid >> 6;
  const int lane = tid & 63;
  const int cc   = lane & 15;
  const int hi   = lane >> 4;
  const int b0g  = blockIdx.x * 16;
  const float L2E = 1.44269504089f;

  // ---- weight B-fragments into VGPRs (pre-scaled; gt: 0=i,1=f,2=g,3=o) ----
  uint4 wB0[4][2], wB1[4][2], wB2[4][2];
  float bias0v[4], wih0v[4];
  f32x4 bi1[4];
  #pragma unroll
  for (int gt = 0; gt < 4; ++gt) {
    float sc = (gt == 2) ? 2.0f * L2E : L2E;
    int row = (wave + 4 * gt) * 16 + cc;
    #pragma unroll
    for (int f = 0; f < 2; ++f) {
      int col = f * 32 + hi * 8;
      wB0[gt][f] = pack8s(Whh0 + row * 64 + col, sc);
      wB1[gt][f] = pack8s(Wih1 + row * 64 + col, sc);
      wB2[gt][f] = pack8s(Whh1 + row * 64 + col, sc);
    }
    bias0v[gt] = (bih0[row] + bhh0[row]) * sc;
    wih0v[gt]  = Wih0[row] * sc;
    float b1c  = (bih1[row] + bhh1[row]) * sc;
    #pragma unroll
    for (int r = 0; r < 4; ++r) bi1[gt][r] = b1c;
  }
  // MLP fragments (waves 0,1 use them; 2,3 load duplicates harmlessly)
  uint4 wM[2];
  {
    int row = (wave & 1) * 16 + cc;
    wM[0] = pack8s(W1 + row * 64 + hi * 8, 1.0f);
    wM[1] = pack8s(W1 + row * 64 + 32 + hi * 8, 1.0f);
  }
  const float w2v  = W2[(wave & 1) * 16 + cc];
  const float b1vv = b1[(wave & 1) * 16 + cc];
  const float alpha  = rcp_(1.0f + exp2_(-L2E * damping[0]));
  const int   nsteps = stepsPtr[0];
  const float b2v    = b2[0];

  // window init: win[t*16+b] = x[(b0g+b)*24 + t]
  for (int e = tid; e < 384; e += NTHR) {
    int b = e & 15, t = e >> 4;
    win[t * 16 + b] = x[(b0g + b) * 24 + t];
  }
  __syncthreads();

  const int offA = cc * SRB + hi * 16;           // A-frag byte offset
  const int offS = (wave * 16 + cc) * 2;         // elementwise store offset
  float prevp = 0.0f;

  for (int s = 0; s < nsteps; ++s) {
    float c1[4] = {0, 0, 0, 0}, c2s[4] = {0, 0, 0, 0};

    // ---- prologue: L0(0) elementwise only (h1(-1)=0) -> h1s[0] ----
    {
      float4 xw = *(const float4*)&win[(s % 24) * 16 + hi * 4];
      float xa[4] = {xw.x, xw.y, xw.z, xw.w};
      #pragma unroll
      for (int r = 0; r < 4; ++r) {
        float hv = gatestep(fmaf(xa[r], wih0v[0], bias0v[0]),
                            fmaf(xa[r], wih0v[1], bias0v[1]),
                            fmaf(xa[r], wih0v[2], bias0v[2]),
                            fmaf(xa[r], wih0v[3], bias0v[3]), c1[r]);
        *(_Float16*)(h1s[0] + (hi * 4 + r) * SRB + offS) = (_Float16)hv;
      }
    }
    __syncthreads();
    uint4 a1lo = *(const uint4*)(h1s[0] + offA);
    uint4 a1hi = *(const uint4*)(h1s[0] + offA + 64);
    uint4 a2lo = make_uint4(0, 0, 0, 0), a2hi = make_uint4(0, 0, 0, 0);

    // ---- main pipelined loop: iter t computes L1(t) and L0(t+1) ----
    for (int t = 0; t < 23; ++t) {
      int pb = (t + 1) & 1;
      int ph = s + t + 1; if (ph >= 24) ph -= 24;
      float4 xw = *(const float4*)&win[ph * 16 + hi * 4];
      float xa[4] = {xw.x, xw.y, xw.z, xw.w};

      f32x4 acc1[4], acc0[4];
      #pragma unroll
      for (int gt = 0; gt < 4; ++gt) {
        f32x4 tv = mfma16(a1lo, wB1[gt][0], bi1[gt]);
        tv = mfma16(a1hi, wB1[gt][1], tv);
        tv = mfma16(a2lo, wB2[gt][0], tv);
        acc1[gt] = mfma16(a2hi, wB2[gt][1], tv);
      }
      #pragma unroll
      for (int gt = 0; gt < 4; ++gt) {
        f32x4 ai;
        #pragma unroll
        for (int r = 0; r < 4; ++r) ai[r] = fmaf(xa[r], wih0v[gt], bias0v[gt]);
        f32x4 tv = mfma16(a1lo, wB0[gt][0], ai);
        acc0[gt] = mfma16(a1hi, wB0[gt][1], tv);
      }

      char* h2d = h2s[pb];
      char* h1d = h1s[pb];
      #pragma unroll
      for (int r = 0; r < 4; ++r) {
        float hv = gatestep(acc1[0][r], acc1[1][r], acc1[2][r], acc1[3][r], c2s[r]);
        *(_Float16*)(h2d + (hi * 4 + r) * SRB + offS) = (_Float16)hv;
      }
      #pragma unroll
      for (int r = 0; r < 4; ++r) {
        float hv = gatestep(acc0[0][r], acc0[1][r], acc0[2][r], acc0[3][r], c1[r]);
        *(_Float16*)(h1d + (hi * 4 + r) * SRB + offS) = (_Float16)hv;
      }
      __syncthreads();
      a1lo = *(const uint4*)(h1s[pb] + offA);
      a1hi = *(const uint4*)(h1s[pb] + offA + 64);
      a2lo = *(const uint4*)(h2s[pb] + offA);
      a2hi = *(const uint4*)(h2s[pb] + offA + 64);
    } // t

    // ---- epilogue: L1(23) -> h2s[0] ----
    {
      f32x4 acc1[4];
      #pragma unroll
      for (int gt = 0; gt < 4; ++gt) {
        f32x4 tv = mfma16(a1lo, wB1[gt][0], bi1[gt]);
        tv = mfma16(a1hi, wB1[gt][1], tv);
        tv = mfma16(a2lo, wB2[gt][0], tv);
        acc1[gt] = mfma16(a2hi, wB2[gt][1], tv);
      }
      #pragma unroll
      for (int r = 0; r < 4; ++r) {
        float cv = c2s[r];
        float hv = gatestep(acc1[0][r], acc1[1][r], acc1[2][r], acc1[3][r], cv);
        *(_Float16*)(h2s[0] + (hi * 4 + r) * SRB + offS) = (_Float16)hv;
      }
    }
    __syncthreads();

    // ---- MLP head on h2(23) (waves 0,1) ----
    if (wave < 2) {
      uint4 hflo = *(const uint4*)(h2s[0] + offA);
      uint4 hfhi = *(const uint4*)(h2s[0] + offA + 64);
      f32x4 am;
      #pragma unroll
      for (int r = 0; r < 4; ++r) am[r] = b1vv;
      am = mfma16(hflo, wM[0], am);
      am = mfma16(hfhi, wM[1], am);
      float yp[4];
      #pragma unroll
      for (int r = 0; r < 4; ++r) yp[r] = fmaxf(am[r], 0.0f) * w2v;
      #pragma unroll
      for (int mask = 1; mask <= 8; mask <<= 1) {
        #pragma unroll
        for (int r = 0; r < 4; ++r) yp[r] += __shfl_xor(yp[r], mask);
      }
      if (cc == 0) {
        #pragma unroll
        for (int r = 0; r < 4; ++r) pm[wave][hi * 4 + r] = yp[r];
      }
    }
    __syncthreads();

    if (wave == 0 && lane < 16) {
      float y = pm[0][lane] + pm[1][lane] + b2v;
      float pd = (s == 0) ? y : fmaf(y, 1.0f - alpha, prevp * (alpha * 0.5f));
      prevp = pd;
      win[(s % 24) * 16 + lane] = pd;
      out[(long)(b0g + lane) * nsteps + s] = pd;
    }
    __syncthreads();
  } // s
}

extern "C" void kernel_launch(void* const* d_in, const int* in_sizes, int n_in,
                              void* d_out, int out_size, void* d_ws, size_t ws_size,
                              hipStream_t stream) {
  (void)in_sizes; (void)n_in; (void)out_size; (void)d_ws; (void)ws_size;
  lstm_forecast<<<NBLK, NTHR, 0, stream>>>(
      (const float*)d_in[0],
      (const float*)d_in[1],  (const float*)d_in[2],
      (const float*)d_in[3],  (const float*)d_in[4],
      (const float*)d_in[5],  (const float*)d_in[6],
      (const float*)d_in[7],  (const float*)d_in[8],
      (const float*)d_in[9],  (const float*)d_in[10],
      (const float*)d_in[11], (const float*)d_in[12],
      (const float*)d_in[13], (const int*)d_in[14],
      (float*)d_out);
}